// Round 20
// baseline (107.322 us; speedup 1.0000x reference)
//
#include <hip/hip_runtime.h>
#include <hip/hip_bf16.h>
#include <cstdint>
#include <cmath>

#define DEVINL __device__ __forceinline__

typedef __attribute__((ext_vector_type(8)))  __bf16 b8;     // MFMA A/B operand (4 VGPRs)
typedef __attribute__((ext_vector_type(4)))  float  f4;     // 16x16 C/D
typedef __attribute__((ext_vector_type(16))) float  f16v;   // 32x32 C/D
typedef __attribute__((ext_vector_type(4)))  unsigned int u32x4;

// f32 -> bf16 round-to-nearest-even (finite inputs only)
DEVINL unsigned short f2bf(float f){
  unsigned int u = __float_as_uint(f);
  u += 0x7FFFu + ((u >> 16) & 1u);
  return (unsigned short)(u >> 16);
}

DEVINL void gl_lds16(const void* g, void* l){
  __builtin_amdgcn_global_load_lds(
      (const __attribute__((address_space(1))) void*)g,
      (__attribute__((address_space(3))) void*)l, 16, 0, 0);
}

DEVINL f16v mfma32(b8 a, b8 b, f16v c){
  return __builtin_amdgcn_mfma_f32_32x32x16_bf16(a, b, c, 0, 0, 0);
}

DEVINL float exp2a(float x){           // v_exp_f32 = 2^x
  float r; asm("v_exp_f32 %0, %1" : "=v"(r) : "v"(x)); return r;
}
DEVINL unsigned int cvtpk(float lo, float hi){   // dst = {bf16(lo), bf16(hi)}
  unsigned int r; asm("v_cvt_pk_bf16_f32 %0, %1, %2" : "=v"(r) : "v"(lo), "v"(hi)); return r;
}
DEVINL void plswap(unsigned int &a, unsigned int &b){
  asm("v_permlane32_swap_b32 %0, %1" : "+v"(a), "+v"(b));
}

#define BARRAW() asm volatile("s_barrier" ::: "memory")
#define WCNT(N)  asm volatile("s_waitcnt vmcnt(" #N ")" ::: "memory")

// ---------------- fused prep kernel ----------------
// One kernel, block-uniform branch on blockIdx range:
//   [0,1024)     cast x f32 -> bf16 (each thread 4x float4)
//   [1024,4096)  transpose-cast wqkv [1024][3072] -> [3072][1024] bf16
//   [4096,5120)  transpose-cast wproj [1024][1024] -> [1024][1024] bf16
//   [5120,5376)  rope table: rtab[n][i] = (cos, sin)(n * 10000^(-i/32))

__global__ __launch_bounds__(256) void prep_k(const float* __restrict__ x,
                                              const float* __restrict__ wqkv,
                                              const float* __restrict__ wproj,
                                              unsigned short* __restrict__ xb,
                                              unsigned short* __restrict__ wqkvT,
                                              unsigned short* __restrict__ wprojT,
                                              float2* __restrict__ rtab){
  __shared__ float t[32][33];
  const int b = blockIdx.x, tid = threadIdx.x;
  if (b < 1024){
    int i = b * 256 + tid;
    #pragma unroll
    for (int it = 0; it < 4; it++){
      float4 v = ((const float4*)x)[i];
      ushort4 o; o.x = f2bf(v.x); o.y = f2bf(v.y); o.z = f2bf(v.z); o.w = f2bf(v.w);
      ((ushort4*)xb)[i] = o;
      i += 1024 * 256;
    }
  } else if (b < 5120){
    const float* in; unsigned short* out; int N2, tt;
    if (b < 4096){ in = wqkv;  out = wqkvT;  N2 = 3072; tt = b - 1024; }
    else         { in = wproj; out = wprojT; N2 = 1024; tt = b - 4096; }
    const int K2 = 1024;
    int nx = (tt % (N2 / 32)) * 32, kx = (tt / (N2 / 32)) * 32;
    int tx = tid & 31, ty = tid >> 5;
    #pragma unroll
    for (int i2 = 0; i2 < 4; i2++)
      t[ty + 8 * i2][tx] = in[(size_t)(kx + ty + 8 * i2) * N2 + nx + tx];
    __syncthreads();
    #pragma unroll
    for (int i2 = 0; i2 < 4; i2++)
      out[(size_t)(nx + ty + 8 * i2) * K2 + kx + tx] = f2bf(t[tx][ty + 8 * i2]);
  } else {
    int tr = (b - 5120) * 256 + tid;
    int n = tr >> 5, i2 = tr & 31;
    float invf = expf(-(float)i2 * (9.210340371976184f / 32.0f));
    float ph = (float)n * invf;
    float s, c;
    sincosf(ph, &s, &c);
    rtab[tr] = make_float2(c, s);
  }
}

// ------------- 256xBN GEMM, BK=64, 8 waves (4M x 2N), 32x32x16 MFMA ----------------
// R19->R20: mfma16 -> mfma32 (32x32x16): m119 measured +15% per-instruction MFMA
// throughput AND half the MFMA instruction count (24 vs 48 per K-tile for QKV) at
// IDENTICAL ds_read count (20/tile) and identical staging/swizzle. C/D layout
// row=(r&3)+8*(r>>2)+4*lam, col=l31 — same mapping attn has used (verified) since R1.
// 4Mx2N wave grid; per-wave output 64 x (NREP*32). XCD-chunked remap (bijective).
// Grid 16x16 = 256 blocks = 1/CU. Per K-tile: compute(slot); barrier;
// stage(next->slot); vmcnt(4+NREP) [counted, never 0 mid-loop]; barrier.

template<int NREP, int EPI>
__global__ __launch_bounds__(512, 2) void gemm256_k(const unsigned short* __restrict__ A,
                                                    const unsigned short* __restrict__ Bt, int N,
                                                    float* __restrict__ Of,
                                                    unsigned short* __restrict__ Qg,
                                                    unsigned short* __restrict__ Kg,
                                                    unsigned short* __restrict__ Vt,
                                                    const float2* __restrict__ rtab){
  constexpr int K = 1024;
  __shared__ unsigned short As[2][256 * 64];        // 32KB per slot
  __shared__ unsigned short Bs[2][NREP * 64 * 64];  // BN x 64, NREP*8KB per slot
  const int tid = threadIdx.x, w = tid >> 6, l = tid & 63;
  const int l31 = l & 31, lam = l >> 5;
  const int wm = w >> 1, wn = w & 1;                // 4M x 2N wave grid
  // XCD-chunked remap: id%8 = XCD; each XCD owns a 4m x 8n block region
  const int id = blockIdx.x + blockIdx.y * 16;      // 0..255
  const int xcd = id & 7, jj2 = id >> 3;            // 32 blocks per XCD
  const int mblk = (xcd >> 1) * 4 + (jj2 >> 3);     // 0..15
  const int nblk = (xcd & 1) * 8 + (jj2 & 7);       // 0..15
  const int m0 = mblk * 256, n0 = nblk * (NREP * 64);

  f16v acc[2][NREP];
  #pragma unroll
  for (int i = 0; i < 2; i++)
    #pragma unroll
    for (int j = 0; j < NREP; j++)
      #pragma unroll
      for (int e = 0; e < 16; e++) acc[i][j][e] = 0.f;

  const int srow8 = (l >> 3);                       // row within 8-row chunk
  const int ssrc  = ((l & 7) ^ (srow8 & 7)) * 8;    // pre-swizzled source slot (elems)

  auto stage = [&](int slot, int kt){
    const unsigned short* Ab = A + kt * 64 + ssrc;
    #pragma unroll
    for (int c2 = 0; c2 < 4; c2++){
      int ch = w * 4 + c2;                          // 32 A-chunks (256 rows)
      gl_lds16(Ab + (size_t)(m0 + ch * 8 + srow8) * K, (char*)&As[slot][0] + ch * 1024);
    }
    const unsigned short* Bb = Bt + kt * 64 + ssrc;
    #pragma unroll
    for (int c2 = 0; c2 < NREP; c2++){
      int ch = w * NREP + c2;                       // BN/8 B-chunks
      gl_lds16(Bb + (size_t)(n0 + ch * 8 + srow8) * K, (char*)&Bs[slot][0] + ch * 1024);
    }
  };

  auto compute = [&](int slot){
    const char* At  = (const char*)&As[slot][0];
    const char* Btl = (const char*)&Bs[slot][0];
    #pragma unroll
    for (int ks = 0; ks < 4; ks++){                 // 4 K-steps of 16
      b8 af[2], bf[NREP];
      int sb = ks * 2 + lam;                        // logical 16B slot 0..7
      #pragma unroll
      for (int mi = 0; mi < 2; mi++){
        int r = wm * 64 + mi * 32 + l31;
        af[mi] = *(const b8*)(At + r * 128 + ((sb ^ (r & 7)) * 16));
      }
      #pragma unroll
      for (int ni = 0; ni < NREP; ni++){
        int r = wn * (NREP * 32) + ni * 32 + l31;
        bf[ni] = *(const b8*)(Btl + r * 128 + ((sb ^ (r & 7)) * 16));
      }
      __builtin_amdgcn_s_setprio(1);
      #pragma unroll
      for (int mi = 0; mi < 2; mi++)
        #pragma unroll
        for (int ni = 0; ni < NREP; ni++)
          acc[mi][ni] = mfma32(af[mi], bf[ni], acc[mi][ni]);
      __builtin_amdgcn_s_setprio(0);
    }
  };

  auto wcnt_stg = [&](){                            // keep newest (4+NREP) outstanding
    if constexpr (NREP == 4)      WCNT(8);
    else if constexpr (NREP == 3) WCNT(7);
    else if constexpr (NREP == 2) WCNT(6);
    else                          WCNT(5);
  };

  // prologue: slot0 <- tile0 (landed), slot1 <- tile1 (in flight)
  stage(0, 0);
  stage(1, 1);
  wcnt_stg();
  BARRAW();
  for (int i = 0; i < 8; i++){
    compute(0);                                     // tile 2i
    BARRAW();
    if (i < 7){ stage(0, 2 * i + 2); wcnt_stg(); }
    else      { WCNT(0); }
    BARRAW();
    compute(1);                                     // tile 2i+1
    BARRAW();
    if (i < 7){ stage(1, 2 * i + 3); wcnt_stg(); }
    BARRAW();
  }

  if constexpr (EPI == 0){
    const float qscale = 0.18033688011112042f;      // 0.125 * log2(e), folded into Q
    const int bb2 = m0 >> 11;
    #pragma unroll
    for (int mi = 0; mi < 2; mi++){
      #pragma unroll
      for (int ni = 0; ni < NREP; ni++){
        f16v a = acc[mi][ni];
        int c = n0 + wn * (NREP * 32) + ni * 32 + l31;
        int s = c >> 10;                            // wave-uniform per 32-col fragment
        int d = c & 63, h = (c >> 6) & 15;
        if (s == 2){
          // V: regs 4*q2..4*q2+3 hold 4 consecutive m -> ushort4 pack along n of Vt
          #pragma unroll
          for (int q2 = 0; q2 < 4; q2++){
            int ns0 = (m0 & 2047) + wm * 64 + mi * 32 + q2 * 8 + 4 * lam;
            ushort4 pv;
            pv.x = f2bf(a[4 * q2 + 0]); pv.y = f2bf(a[4 * q2 + 1]);
            pv.z = f2bf(a[4 * q2 + 2]); pv.w = f2bf(a[4 * q2 + 3]);
            *(ushort4*)(Vt + (((size_t)(bb2 * 16 + h) * 64 + d) << 11) + ns0) = pv;
          }
        } else {
          #pragma unroll
          for (int r = 0; r < 16; r++){
            int m = m0 + wm * 64 + mi * 32 + (r & 3) + 8 * (r >> 2) + 4 * lam;
            int bb = m >> 11, ns = m & 2047;
            size_t didx = ((size_t)(bb * 16 + h) * 2048 + ns) * 64 + d;
            float part = __shfl_xor(a[r], 1);       // pair partner (d^1 = l31^1)
            float2 cs = rtab[ns * 32 + (d >> 1)];
            float val = (d & 1) ? (a[r] * cs.x + part * cs.y)
                                : (a[r] * cs.x - part * cs.y);
            if (s == 0){ Qg[didx] = f2bf(val * qscale); }
            else       { Kg[didx] = f2bf(val); }
          }
        }
      }
    }
  } else {
    #pragma unroll
    for (int mi = 0; mi < 2; mi++)
      #pragma unroll
      for (int ni = 0; ni < NREP; ni++){
        int c = n0 + wn * (NREP * 32) + ni * 32 + l31;
        #pragma unroll
        for (int r = 0; r < 16; r++){
          int m = m0 + wm * 64 + mi * 32 + (r & 3) + 8 * (r >> 2) + 4 * lam;
          Of[(size_t)m * N + c] = acc[mi][ni][r];
        }
      }
  }
}

// ---------------- flash attention: R15/R19 best-known version ----------------
// 2-buffer, 64-kv tiles, counted vmcnt(4), 2 barriers/tile, no setprio.
// Fixed-shift softmax (P = exp2(st)); lrow via ones-MFMA.
// Qg/Kg: [32 g][2048 n][64 d] bf16 (Q pre-scaled by 0.125*log2e). Vt: [32 g][64 d][2048 n].

__global__ __launch_bounds__(256) void attn_k(const unsigned short* __restrict__ Qg,
                                              const unsigned short* __restrict__ Kg,
                                              const unsigned short* __restrict__ Vt,
                                              unsigned short* __restrict__ Ao){
  __shared__ unsigned short Ks[2][4096];   // [buf][64 kv][64 d], swizzled chunks
  __shared__ unsigned short Vs[2][4096];   // [buf][64 d][64 kv], swizzled chunks
  const int tid = threadIdx.x, w = tid >> 6, l = tid & 63;
  const int l31 = l & 31, lam = l >> 5;

  // XCD-aware remap: each XCD owns 4 heads -> K/V L2-resident (2 MB/XCD)
  const int id = blockIdx.x + blockIdx.y * 16;      // grid (16,32)
  const int xc = id & 7, j = id >> 3;
  const int g = xc * 4 + (j & 3), qb = j >> 2;
  const int q0 = qb * 128 + w * 32;
  const size_t hb = (size_t)g << 17;                // g * 2048*64

  // Q fragments: qf[kd] = Q[q0+l31][16*kd + 8*lam + 0..7]
  b8 qf[4];
  {
    const unsigned short* qrow = Qg + hb + (size_t)(q0 + l31) * 64 + lam * 8;
    #pragma unroll
    for (int kd = 0; kd < 4; kd++) qf[kd] = *(const b8*)(qrow + kd * 16);
  }

  const unsigned short* kgb = Kg + hb;
  const unsigned short* vgb = Vt + hb;
  const int srow = (l >> 3);              // row within chunk
  const int sc8  = ((l & 7) ^ (srow & 7)) * 8;   // pre-swizzled source slot (elems)

  auto stage = [&](int buf, int kv0){     // 4 loads per thread (2 chunks x K,V)
    #pragma unroll
    for (int c = 0; c < 2; c++){
      int chunk = w * 2 + c;
      int r = chunk * 8 + srow;           // 0..63
      gl_lds16(kgb + (size_t)(kv0 + r) * 64 + sc8,
               (char*)&Ks[buf][0] + chunk * 1024);
      gl_lds16(vgb + (size_t)r * 2048 + kv0 + sc8,
               (char*)&Vs[buf][0] + chunk * 1024);
    }
  };

  // B-operand of all bf16 ones for the L row-sum MFMA
  union { u32x4 u; b8 v; } ones;
  ones.u[0] = ones.u[1] = ones.u[2] = ones.u[3] = 0x3F803F80u;

  f16v O[2], L;
  #pragma unroll
  for (int i = 0; i < 16; i++){ O[0][i] = 0.f; O[1][i] = 0.f; L[i] = 0.f; }

  auto tile = [&](int buf){
    b8 kf[8], vf[8];
    const char* ksb = (const char*)&Ks[buf][0];
    const char* vsb = (const char*)&Vs[buf][0];
    const int rsw = (l31 & 7);
    #pragma unroll
    for (int kvb = 0; kvb < 2; kvb++)
      #pragma unroll
      for (int kd = 0; kd < 4; kd++)
        kf[kvb * 4 + kd] = *(const b8*)(ksb + (kvb * 32 + l31) * 128
                                        + (((kd * 2 + lam) ^ rsw) * 16));
    #pragma unroll
    for (int s = 0; s < 4; s++)
      #pragma unroll
      for (int db = 0; db < 2; db++)
        vf[s * 2 + db] = *(const b8*)(vsb + (db * 32 + l31) * 128
                                      + (((2 * s + lam) ^ rsw) * 16));

    f16v st[2];
    #pragma unroll
    for (int i = 0; i < 16; i++){ st[0][i] = 0.f; st[1][i] = 0.f; }
    #pragma unroll
    for (int kd = 0; kd < 4; kd++) st[0] = mfma32(kf[kd],     qf[kd], st[0]);
    #pragma unroll
    for (int kd = 0; kd < 4; kd++) st[1] = mfma32(kf[4 + kd], qf[kd], st[1]);

    // fixed-shift softmax: P = exp2(st) directly (st already in log2 units)
    #pragma unroll
    for (int b2 = 0; b2 < 2; b2++)
      #pragma unroll
      for (int r = 0; r < 16; r++)
        st[b2][r] = exp2a(st[b2][r]);

    // PV + row-sum: per 16-kv slice build P A-frag in-register (T12)
    #pragma unroll
    for (int s = 0; s < 4; s++){
      const int b = s >> 1, base = (s & 1) * 8;
      unsigned int pA = cvtpk(st[b][base + 0], st[b][base + 1]);
      unsigned int pB = cvtpk(st[b][base + 2], st[b][base + 3]);
      unsigned int pC = cvtpk(st[b][base + 4], st[b][base + 5]);
      unsigned int pD = cvtpk(st[b][base + 6], st[b][base + 7]);
      plswap(pA, pC); plswap(pB, pD);
      union { u32x4 u; b8 v; } pf;
      pf.u[0] = pA; pf.u[1] = pB; pf.u[2] = pC; pf.u[3] = pD;
      O[0] = mfma32(pf.v, vf[s * 2 + 0], O[0]);
      O[1] = mfma32(pf.v, vf[s * 2 + 1], O[1]);
      L    = mfma32(pf.v, ones.v,       L);
    }
  };

  // counted-vmcnt pipeline (T3+T4): prologue stages tiles 0,1; vmcnt(4) waits the
  // PREVIOUS stage only (4 loads/thread/stage); no mid-loop vmcnt(0) drain.
  stage(0, 0);
  stage(1, 64);
  WCNT(4);                                // tile0 landed; tile1 in flight
  BARRAW();
  for (int i = 0; i < 16; i++){
    tile(0);                              // tile 2i
    BARRAW();                             // all waves done reading buf0
    if (i < 15){ stage(0, (2 * i + 2) * 64); WCNT(4); }   // waits buf1's stage
    else       { WCNT(0); }
    BARRAW();                             // buf1 writes visible to all waves
    tile(1);                              // tile 2i+1
    BARRAW();
    if (i < 15){ stage(1, (2 * i + 3) * 64); WCNT(4); }   // waits buf0's new stage
    BARRAW();
  }

  // finalize: O /= L (each lane holds its rows' sums), store bf16
  const int bb = g >> 4, h = g & 15;
  unsigned short* aoBase = Ao + (size_t)bb * 2048 * 1024 + h * 64 + l31;
  #pragma unroll
  for (int r = 0; r < 16; r++){
    int qr = (r & 3) + 8 * (r >> 2) + 4 * lam;
    float li = 1.0f / L[r];
    size_t rowoff = (size_t)(q0 + qr) * 1024;
    aoBase[rowoff]      = f2bf(O[0][r] * li);
    aoBase[rowoff + 32] = f2bf(O[1][r] * li);
  }
}

// ---------------- launch ----------------

extern "C" void kernel_launch(void* const* d_in, const int* in_sizes, int n_in,
                              void* d_out, int out_size, void* d_ws, size_t ws_size,
                              hipStream_t stream){
  const float* x     = (const float*)d_in[0];   // [2,2048,1024]
  const float* wqkv  = (const float*)d_in[1];   // [1024,3072]
  const float* wproj = (const float*)d_in[2];   // [1024,1024]
  float* out = (float*)d_out;                   // [2,2048,1024] f32

  if (ws_size < 42467328u) return;
  char* ws = (char*)d_ws;
  unsigned short* xb     = (unsigned short*)(ws);             // 8 MB
  unsigned short* wqkvT  = (unsigned short*)(ws + 8388608);   // 6 MB  [3072][1024]
  unsigned short* wprojT = (unsigned short*)(ws + 14680064);  // 2 MB  [1024][1024]
  float2*         rtab   = (float2*)(ws + 16777216);          // 512 KB
  unsigned short* Qg     = (unsigned short*)(ws + 17301504);  // 8 MB  [32][2048][64]
  unsigned short* Kg     = (unsigned short*)(ws + 25690112);  // 8 MB  [32][2048][64]
  unsigned short* Vt     = (unsigned short*)(ws + 34078720);  // 8 MB  [32][64][2048]
  unsigned short* Ao     = xb;                                // reuse (xb dead after QKV gemm)

  prep_k<<<5376, 256, 0, stream>>>(x, wqkv, wproj, xb, wqkvT, wprojT, rtab);
  gemm256_k<3, 0><<<dim3(16, 16), 512, 0, stream>>>(xb, wqkvT, 3072, nullptr, Qg, Kg, Vt, rtab);
  attn_k<<<dim3(16, 32), 256, 0, stream>>>(Qg, Kg, Vt, Ao);
  gemm256_k<1, 1><<<dim3(16, 16), 512, 0, stream>>>(Ao, wprojT, 1024, out, nullptr, nullptr, nullptr, nullptr);
}

// Round 21
// 106.377 us; speedup vs baseline: 1.0089x; 1.0089x over previous
//
#include <hip/hip_runtime.h>
#include <hip/hip_bf16.h>
#include <cstdint>
#include <cmath>

#define DEVINL __device__ __forceinline__

typedef __attribute__((ext_vector_type(8)))  __bf16 b8;     // MFMA A/B operand (4 VGPRs)
typedef __attribute__((ext_vector_type(4)))  float  f4;     // 16x16 C/D
typedef __attribute__((ext_vector_type(16))) float  f16v;   // 32x32 C/D
typedef __attribute__((ext_vector_type(4)))  unsigned int u32x4;

// f32 -> bf16 round-to-nearest-even (finite inputs only)
DEVINL unsigned short f2bf(float f){
  unsigned int u = __float_as_uint(f);
  u += 0x7FFFu + ((u >> 16) & 1u);
  return (unsigned short)(u >> 16);
}

DEVINL void gl_lds16(const void* g, void* l){
  __builtin_amdgcn_global_load_lds(
      (const __attribute__((address_space(1))) void*)g,
      (__attribute__((address_space(3))) void*)l, 16, 0, 0);
}

DEVINL f4 mfma16(b8 a, b8 b, f4 c){
  return __builtin_amdgcn_mfma_f32_16x16x32_bf16(a, b, c, 0, 0, 0);
}
DEVINL f16v mfma32(b8 a, b8 b, f16v c){
  return __builtin_amdgcn_mfma_f32_32x32x16_bf16(a, b, c, 0, 0, 0);
}

DEVINL float exp2a(float x){           // v_exp_f32 = 2^x
  float r; asm("v_exp_f32 %0, %1" : "=v"(r) : "v"(x)); return r;
}
DEVINL unsigned int cvtpk(float lo, float hi){   // dst = {bf16(lo), bf16(hi)}
  unsigned int r; asm("v_cvt_pk_bf16_f32 %0, %1, %2" : "=v"(r) : "v"(lo), "v"(hi)); return r;
}
DEVINL void plswap(unsigned int &a, unsigned int &b){
  asm("v_permlane32_swap_b32 %0, %1" : "+v"(a), "+v"(b));
}

#define BARRAW() asm volatile("s_barrier" ::: "memory")
#define WCNT(N)  asm volatile("s_waitcnt vmcnt(" #N ")" ::: "memory")

// ---------------- fused prep kernel ----------------
// One kernel, block-uniform branch on blockIdx range:
//   [0,1024)     cast x f32 -> bf16 (each thread 4x float4)
//   [1024,4096)  transpose-cast wqkv [1024][3072] -> [3072][1024] bf16
//   [4096,5120)  transpose-cast wproj [1024][1024] -> [1024][1024] bf16
//   [5120,5376)  rope table: rtab[n][i] = (cos, sin)(n * 10000^(-i/32))

__global__ __launch_bounds__(256) void prep_k(const float* __restrict__ x,
                                              const float* __restrict__ wqkv,
                                              const float* __restrict__ wproj,
                                              unsigned short* __restrict__ xb,
                                              unsigned short* __restrict__ wqkvT,
                                              unsigned short* __restrict__ wprojT,
                                              float2* __restrict__ rtab){
  __shared__ float t[32][33];
  const int b = blockIdx.x, tid = threadIdx.x;
  if (b < 1024){
    int i = b * 256 + tid;
    #pragma unroll
    for (int it = 0; it < 4; it++){
      float4 v = ((const float4*)x)[i];
      ushort4 o; o.x = f2bf(v.x); o.y = f2bf(v.y); o.z = f2bf(v.z); o.w = f2bf(v.w);
      ((ushort4*)xb)[i] = o;
      i += 1024 * 256;
    }
  } else if (b < 5120){
    const float* in; unsigned short* out; int N2, tt;
    if (b < 4096){ in = wqkv;  out = wqkvT;  N2 = 3072; tt = b - 1024; }
    else         { in = wproj; out = wprojT; N2 = 1024; tt = b - 4096; }
    const int K2 = 1024;
    int nx = (tt % (N2 / 32)) * 32, kx = (tt / (N2 / 32)) * 32;
    int tx = tid & 31, ty = tid >> 5;
    #pragma unroll
    for (int i2 = 0; i2 < 4; i2++)
      t[ty + 8 * i2][tx] = in[(size_t)(kx + ty + 8 * i2) * N2 + nx + tx];
    __syncthreads();
    #pragma unroll
    for (int i2 = 0; i2 < 4; i2++)
      out[(size_t)(nx + ty + 8 * i2) * K2 + kx + tx] = f2bf(t[tx][ty + 8 * i2]);
  } else {
    int tr = (b - 5120) * 256 + tid;
    int n = tr >> 5, i2 = tr & 31;
    float invf = expf(-(float)i2 * (9.210340371976184f / 32.0f));
    float ph = (float)n * invf;
    float s, c;
    sincosf(ph, &s, &c);
    rtab[tr] = make_float2(c, s);
  }
}

// ------------- 256xBN GEMM, BK=64, 8 waves (4M x 2N), counted-vmcnt schedule ----------
// R20 post-mortem: mfma32 variant was neutral (GEMMs latency-bound, not MFMA-issue
// bound) — REVERTED to the R19 best-measured mfma16 version.
// 4Mx2N wave grid (R15: -5us vs 2Mx4N; LDS-read amplification cut).
// XCD-chunked block remap (bijective). Grid 16x16 = 256 blocks = 1/CU.
// Per K-tile: compute(slot); barrier; stage(next->slot); vmcnt(4+NREP); barrier.

template<int NREP, int EPI>
__global__ __launch_bounds__(512, 2) void gemm256_k(const unsigned short* __restrict__ A,
                                                    const unsigned short* __restrict__ Bt, int N,
                                                    float* __restrict__ Of,
                                                    unsigned short* __restrict__ Qg,
                                                    unsigned short* __restrict__ Kg,
                                                    unsigned short* __restrict__ Vt,
                                                    const float2* __restrict__ rtab){
  constexpr int K = 1024;
  constexpr int NR2 = 2 * NREP;                     // 16-col fragments per wave
  __shared__ unsigned short As[2][256 * 64];        // 32KB per slot
  __shared__ unsigned short Bs[2][NREP * 64 * 64];  // BN x 64, NREP*8KB per slot
  const int tid = threadIdx.x, w = tid >> 6, l = tid & 63;
  const int wm = w >> 1, wn = w & 1;                // 4M x 2N wave grid
  // XCD-chunked remap: id%8 = XCD; each XCD owns a 4m x 8n block region
  const int id = blockIdx.x + blockIdx.y * 16;      // 0..255
  const int xcd = id & 7, jj2 = id >> 3;            // 32 blocks per XCD
  const int mblk = (xcd >> 1) * 4 + (jj2 >> 3);     // 0..15
  const int nblk = (xcd & 1) * 8 + (jj2 & 7);       // 0..15
  const int m0 = mblk * 256, n0 = nblk * (NREP * 64);

  f4 acc[4][NR2];
  const f4 fz = {0.f, 0.f, 0.f, 0.f};
  #pragma unroll
  for (int i = 0; i < 4; i++)
    #pragma unroll
    for (int j = 0; j < NR2; j++) acc[i][j] = fz;

  const int srow8 = (l >> 3);                       // row within 8-row chunk
  const int ssrc  = ((l & 7) ^ (srow8 & 7)) * 8;    // pre-swizzled source slot (elems)

  auto stage = [&](int slot, int kt){
    const unsigned short* Ab = A + kt * 64 + ssrc;
    #pragma unroll
    for (int c2 = 0; c2 < 4; c2++){
      int ch = w * 4 + c2;                          // 32 A-chunks (256 rows)
      gl_lds16(Ab + (size_t)(m0 + ch * 8 + srow8) * K, (char*)&As[slot][0] + ch * 1024);
    }
    const unsigned short* Bb = Bt + kt * 64 + ssrc;
    #pragma unroll
    for (int c2 = 0; c2 < NREP; c2++){
      int ch = w * NREP + c2;                       // BN/8 B-chunks
      gl_lds16(Bb + (size_t)(n0 + ch * 8 + srow8) * K, (char*)&Bs[slot][0] + ch * 1024);
    }
  };

  auto compute = [&](int slot){
    const char* At  = (const char*)&As[slot][0];
    const char* Btl = (const char*)&Bs[slot][0];
    #pragma unroll
    for (int kk = 0; kk < 2; kk++){
      b8 af[4], bf[NR2];
      int sb = kk * 4 + (l >> 4);                   // logical 16B slot 0..7
      #pragma unroll
      for (int mi = 0; mi < 4; mi++){
        int r = wm * 64 + mi * 16 + (l & 15);
        af[mi] = *(const b8*)(At + r * 128 + ((sb ^ (r & 7)) * 16));
      }
      #pragma unroll
      for (int ni = 0; ni < NR2; ni++){
        int r = wn * (NREP * 32) + ni * 16 + (l & 15);
        bf[ni] = *(const b8*)(Btl + r * 128 + ((sb ^ (r & 7)) * 16));
      }
      __builtin_amdgcn_s_setprio(1);
      #pragma unroll
      for (int mi = 0; mi < 4; mi++)
        #pragma unroll
        for (int ni = 0; ni < NR2; ni++)
          acc[mi][ni] = mfma16(af[mi], bf[ni], acc[mi][ni]);
      __builtin_amdgcn_s_setprio(0);
    }
  };

  auto wcnt_stg = [&](){                            // keep newest (4+NREP) outstanding
    if constexpr (NREP == 4)      WCNT(8);
    else if constexpr (NREP == 3) WCNT(7);
    else if constexpr (NREP == 2) WCNT(6);
    else                          WCNT(5);
  };

  // prologue: slot0 <- tile0 (landed), slot1 <- tile1 (in flight)
  stage(0, 0);
  stage(1, 1);
  wcnt_stg();
  BARRAW();
  for (int i = 0; i < 8; i++){
    compute(0);                                     // tile 2i
    BARRAW();
    if (i < 7){ stage(0, 2 * i + 2); wcnt_stg(); }
    else      { WCNT(0); }
    BARRAW();
    compute(1);                                     // tile 2i+1
    BARRAW();
    if (i < 7){ stage(1, 2 * i + 3); wcnt_stg(); }
    BARRAW();
  }

  if constexpr (EPI == 0){
    const float qscale = 0.18033688011112042f;      // 0.125 * log2(e), folded into Q
    const int bb2 = m0 >> 11;
    #pragma unroll
    for (int mi = 0; mi < 4; mi++){
      #pragma unroll
      for (int ni = 0; ni < NR2; ni++){
        f4 a = acc[mi][ni];
        int c = n0 + wn * (NREP * 32) + ni * 16 + (l & 15);
        int s = c >> 10;                            // wave-uniform per fragment
        int d = c & 63, h = (c >> 6) & 15;
        if (s == 2){
          int ns0 = (m0 & 2047) + wm * 64 + mi * 16 + (l >> 4) * 4;
          ushort4 pv;
          pv.x = f2bf(a[0]); pv.y = f2bf(a[1]); pv.z = f2bf(a[2]); pv.w = f2bf(a[3]);
          *(ushort4*)(Vt + (((size_t)(bb2 * 16 + h) * 64 + d) << 11) + ns0) = pv;
        } else {
          #pragma unroll
          for (int jj = 0; jj < 4; jj++){
            int m = m0 + wm * 64 + mi * 16 + (l >> 4) * 4 + jj;
            int bb = m >> 11, ns = m & 2047;
            size_t didx = ((size_t)(bb * 16 + h) * 2048 + ns) * 64 + d;
            float part = __shfl_xor(a[jj], 1);
            float2 cs = rtab[ns * 32 + (d >> 1)];
            float val = (d & 1) ? (a[jj] * cs.x + part * cs.y)
                                : (a[jj] * cs.x - part * cs.y);
            if (s == 0){ Qg[didx] = f2bf(val * qscale); }
            else       { Kg[didx] = f2bf(val); }
          }
        }
      }
    }
  } else {
    #pragma unroll
    for (int mi = 0; mi < 4; mi++)
      #pragma unroll
      for (int ni = 0; ni < NR2; ni++){
        int c = n0 + wn * (NREP * 32) + ni * 16 + (l & 15);
        #pragma unroll
        for (int jj = 0; jj < 4; jj++){
          int m = m0 + wm * 64 + mi * 16 + (l >> 4) * 4 + jj;
          Of[(size_t)m * N + c] = acc[mi][ni][jj];
        }
      }
  }
}

// ---------------- flash attention: R15/R19 best-known version (final) ----------------
// 2-buffer, 64-kv tiles, counted vmcnt(4), 2 barriers/tile, no setprio.
// Fixed-shift softmax (P = exp2(st)); lrow via ones-MFMA.
// Qg/Kg: [32 g][2048 n][64 d] bf16 (Q pre-scaled by 0.125*log2e). Vt: [32 g][64 d][2048 n].

__global__ __launch_bounds__(256) void attn_k(const unsigned short* __restrict__ Qg,
                                              const unsigned short* __restrict__ Kg,
                                              const unsigned short* __restrict__ Vt,
                                              unsigned short* __restrict__ Ao){
  __shared__ unsigned short Ks[2][4096];   // [buf][64 kv][64 d], swizzled chunks
  __shared__ unsigned short Vs[2][4096];   // [buf][64 d][64 kv], swizzled chunks
  const int tid = threadIdx.x, w = tid >> 6, l = tid & 63;
  const int l31 = l & 31, lam = l >> 5;

  // XCD-aware remap: each XCD owns 4 heads -> K/V L2-resident (2 MB/XCD)
  const int id = blockIdx.x + blockIdx.y * 16;      // grid (16,32)
  const int xc = id & 7, j = id >> 3;
  const int g = xc * 4 + (j & 3), qb = j >> 2;
  const int q0 = qb * 128 + w * 32;
  const size_t hb = (size_t)g << 17;                // g * 2048*64

  // Q fragments: qf[kd] = Q[q0+l31][16*kd + 8*lam + 0..7]
  b8 qf[4];
  {
    const unsigned short* qrow = Qg + hb + (size_t)(q0 + l31) * 64 + lam * 8;
    #pragma unroll
    for (int kd = 0; kd < 4; kd++) qf[kd] = *(const b8*)(qrow + kd * 16);
  }

  const unsigned short* kgb = Kg + hb;
  const unsigned short* vgb = Vt + hb;
  const int srow = (l >> 3);              // row within chunk
  const int sc8  = ((l & 7) ^ (srow & 7)) * 8;   // pre-swizzled source slot (elems)

  auto stage = [&](int buf, int kv0){     // 4 loads per thread (2 chunks x K,V)
    #pragma unroll
    for (int c = 0; c < 2; c++){
      int chunk = w * 2 + c;
      int r = chunk * 8 + srow;           // 0..63
      gl_lds16(kgb + (size_t)(kv0 + r) * 64 + sc8,
               (char*)&Ks[buf][0] + chunk * 1024);
      gl_lds16(vgb + (size_t)r * 2048 + kv0 + sc8,
               (char*)&Vs[buf][0] + chunk * 1024);
    }
  };

  // B-operand of all bf16 ones for the L row-sum MFMA
  union { u32x4 u; b8 v; } ones;
  ones.u[0] = ones.u[1] = ones.u[2] = ones.u[3] = 0x3F803F80u;

  f16v O[2], L;
  #pragma unroll
  for (int i = 0; i < 16; i++){ O[0][i] = 0.f; O[1][i] = 0.f; L[i] = 0.f; }

  auto tile = [&](int buf){
    b8 kf[8], vf[8];
    const char* ksb = (const char*)&Ks[buf][0];
    const char* vsb = (const char*)&Vs[buf][0];
    const int rsw = (l31 & 7);
    #pragma unroll
    for (int kvb = 0; kvb < 2; kvb++)
      #pragma unroll
      for (int kd = 0; kd < 4; kd++)
        kf[kvb * 4 + kd] = *(const b8*)(ksb + (kvb * 32 + l31) * 128
                                        + (((kd * 2 + lam) ^ rsw) * 16));
    #pragma unroll
    for (int s = 0; s < 4; s++)
      #pragma unroll
      for (int db = 0; db < 2; db++)
        vf[s * 2 + db] = *(const b8*)(vsb + (db * 32 + l31) * 128
                                      + (((2 * s + lam) ^ rsw) * 16));

    f16v st[2];
    #pragma unroll
    for (int i = 0; i < 16; i++){ st[0][i] = 0.f; st[1][i] = 0.f; }
    #pragma unroll
    for (int kd = 0; kd < 4; kd++) st[0] = mfma32(kf[kd],     qf[kd], st[0]);
    #pragma unroll
    for (int kd = 0; kd < 4; kd++) st[1] = mfma32(kf[4 + kd], qf[kd], st[1]);

    // fixed-shift softmax: P = exp2(st) directly (st already in log2 units)
    #pragma unroll
    for (int b2 = 0; b2 < 2; b2++)
      #pragma unroll
      for (int r = 0; r < 16; r++)
        st[b2][r] = exp2a(st[b2][r]);

    // PV + row-sum: per 16-kv slice build P A-frag in-register (T12)
    #pragma unroll
    for (int s = 0; s < 4; s++){
      const int b = s >> 1, base = (s & 1) * 8;
      unsigned int pA = cvtpk(st[b][base + 0], st[b][base + 1]);
      unsigned int pB = cvtpk(st[b][base + 2], st[b][base + 3]);
      unsigned int pC = cvtpk(st[b][base + 4], st[b][base + 5]);
      unsigned int pD = cvtpk(st[b][base + 6], st[b][base + 7]);
      plswap(pA, pC); plswap(pB, pD);
      union { u32x4 u; b8 v; } pf;
      pf.u[0] = pA; pf.u[1] = pB; pf.u[2] = pC; pf.u[3] = pD;
      O[0] = mfma32(pf.v, vf[s * 2 + 0], O[0]);
      O[1] = mfma32(pf.v, vf[s * 2 + 1], O[1]);
      L    = mfma32(pf.v, ones.v,       L);
    }
  };

  // counted-vmcnt pipeline (T3+T4): prologue stages tiles 0,1; vmcnt(4) waits the
  // PREVIOUS stage only (4 loads/thread/stage); no mid-loop vmcnt(0) drain.
  stage(0, 0);
  stage(1, 64);
  WCNT(4);                                // tile0 landed; tile1 in flight
  BARRAW();
  for (int i = 0; i < 16; i++){
    tile(0);                              // tile 2i
    BARRAW();                             // all waves done reading buf0
    if (i < 15){ stage(0, (2 * i + 2) * 64); WCNT(4); }   // waits buf1's stage
    else       { WCNT(0); }
    BARRAW();                             // buf1 writes visible to all waves
    tile(1);                              // tile 2i+1
    BARRAW();
    if (i < 15){ stage(1, (2 * i + 3) * 64); WCNT(4); }   // waits buf0's new stage
    BARRAW();
  }

  // finalize: O /= L (each lane holds its rows' sums), store bf16
  const int bb = g >> 4, h = g & 15;
  unsigned short* aoBase = Ao + (size_t)bb * 2048 * 1024 + h * 64 + l31;
  #pragma unroll
  for (int r = 0; r < 16; r++){
    int qr = (r & 3) + 8 * (r >> 2) + 4 * lam;
    float li = 1.0f / L[r];
    size_t rowoff = (size_t)(q0 + qr) * 1024;
    aoBase[rowoff]      = f2bf(O[0][r] * li);
    aoBase[rowoff + 32] = f2bf(O[1][r] * li);
  }
}

// ---------------- launch ----------------

extern "C" void kernel_launch(void* const* d_in, const int* in_sizes, int n_in,
                              void* d_out, int out_size, void* d_ws, size_t ws_size,
                              hipStream_t stream){
  const float* x     = (const float*)d_in[0];   // [2,2048,1024]
  const float* wqkv  = (const float*)d_in[1];   // [1024,3072]
  const float* wproj = (const float*)d_in[2];   // [1024,1024]
  float* out = (float*)d_out;                   // [2,2048,1024] f32

  if (ws_size < 42467328u) return;
  char* ws = (char*)d_ws;
  unsigned short* xb     = (unsigned short*)(ws);             // 8 MB
  unsigned short* wqkvT  = (unsigned short*)(ws + 8388608);   // 6 MB  [3072][1024]
  unsigned short* wprojT = (unsigned short*)(ws + 14680064);  // 2 MB  [1024][1024]
  float2*         rtab   = (float2*)(ws + 16777216);          // 512 KB
  unsigned short* Qg     = (unsigned short*)(ws + 17301504);  // 8 MB  [32][2048][64]
  unsigned short* Kg     = (unsigned short*)(ws + 25690112);  // 8 MB  [32][2048][64]
  unsigned short* Vt     = (unsigned short*)(ws + 34078720);  // 8 MB  [32][64][2048]
  unsigned short* Ao     = xb;                                // reuse (xb dead after QKV gemm)

  prep_k<<<5376, 256, 0, stream>>>(x, wqkv, wproj, xb, wqkvT, wprojT, rtab);
  gemm256_k<3, 0><<<dim3(16, 16), 512, 0, stream>>>(xb, wqkvT, 3072, nullptr, Qg, Kg, Vt, rtab);
  attn_k<<<dim3(16, 32), 256, 0, stream>>>(Qg, Kg, Vt, Ao);
  gemm256_k<1, 1><<<dim3(16, 16), 512, 0, stream>>>(Ao, wprojT, 1024, out, nullptr, nullptr, nullptr, nullptr);
}